// Round 16
// baseline (134.683 us; speedup 1.0000x reference)
//
#include <hip/hip_runtime.h>
#include <math.h>

constexpr int NN = 4;    // batch
constexpr int CC = 128;  // channels

typedef unsigned short u16;
typedef short bfrag __attribute__((ext_vector_type(8)));   // 8 bf16
typedef float facc  __attribute__((ext_vector_type(4)));   // 4 f32 acc

__device__ __forceinline__ float bf2f(u16 v) {
    unsigned u = ((unsigned)v) << 16; float f; __builtin_memcpy(&f, &u, 4); return f;
}
__device__ __forceinline__ u16 f2bf(float f) {
    unsigned u; __builtin_memcpy(&u, &f, 4);
    unsigned r = u + 0x7FFFu + ((u >> 16) & 1u);
    return (u16)(r >> 16);
}

typedef const __attribute__((address_space(1))) unsigned int gu32;
typedef __attribute__((address_space(3))) unsigned int lu32;
__device__ __forceinline__ void gload16(const u16* g, u16* l) {
    __builtin_amdgcn_global_load_lds((gu32*)g, (lu32*)l, 16, 0, 0);
}

// =====================================================================
// Halo-LDS 3x3 conv GEMM (unchanged, verified R5-R15).
// =====================================================================
template<int WM, int WN, int MR, int NR, int NOB, int EPI>
__global__ __launch_bounds__(512)
void gconv_h(const u16* __restrict__ A, const u16* __restrict__ Wp,
             const float* __restrict__ bias, void* __restrict__ Out,
             int H, int W, int npb)
{
    constexpr int HALOW = 68;
    __shared__ __align__(16) u16 halo[4 * HALOW * 128];    // 69632 B

    const int Hp = H + 2, Wq = W + 2, HW = H * W;
    const int tid = threadIdx.x, lane = tid & 63, wv = tid >> 6;
    const int wn = wv % WN, wm = wv / WN;
    const int colc = lane & 15, kg = lane >> 4;
    const int n = blockIdx.x / npb;
    const int pib = (blockIdx.x - n * npb) * 64;
    const int ymin = pib / W;

    {
        const u16* Abase = A + (size_t)n * Hp * Wq * 128;
        for (int c = wv; c < 4 * HALOW / 4; c += 8) {
            int o = c * 512 + lane * 8;
            int r = o / (HALOW * 128);
            int e = o - r * (HALOW * 128);
            int x = e >> 7;
            int g = (e >> 3) & 15;
            int xs = x < Wq ? x : Wq - 1;
            int pr = ymin + r; if (pr > Hp - 1) pr = Hp - 1;
            const u16* src = Abase + ((size_t)pr * Wq + xs) * 128 + (g ^ (x & 7)) * 8;
            gload16(src, &halo[c * 512]);
        }
    }
    __syncthreads();

    int dyr[MR], axr[MR];
#pragma unroll
    for (int r = 0; r < MR; ++r) {
        int m = wm * (MR * 16) + r * 16 + colc;
        int pixl = pib + m; if (pixl > HW - 1) pixl = HW - 1;
        int y = pixl / W;
        dyr[r] = y - ymin; axr[r] = pixl - y * W;
    }

    auto wfrag = [&](int tap, int cc, int q) -> const bfrag* {
        return (const bfrag*)(Wp + (size_t)tap * (NOB * 2048)
                              + ((cc * NOB + wn * NR + q) * 64 + lane) * 8);
    };

    bfrag bc[4][NR];
#pragma unroll
    for (int cc = 0; cc < 4; ++cc)
#pragma unroll
        for (int q = 0; q < NR; ++q) bc[cc][q] = *wfrag(0, cc, q);

    facc acc[MR][NR];
#pragma unroll
    for (int r = 0; r < MR; ++r)
#pragma unroll
        for (int q = 0; q < NR; ++q) acc[r][q] = (facc){0.f, 0.f, 0.f, 0.f};

#pragma unroll 1
    for (int t = 0; t < 9; ++t) {
        int ty = t / 3, tx = t - ty * 3;
        bfrag bn_[4][NR];
        if (t < 8) {
#pragma unroll
            for (int cc = 0; cc < 4; ++cc)
#pragma unroll
                for (int q = 0; q < NR; ++q) bn_[cc][q] = *wfrag(t + 1, cc, q);
        }
#pragma unroll
        for (int cc = 0; cc < 4; ++cc) {
            bfrag a[MR];
#pragma unroll
            for (int r = 0; r < MR; ++r) {
                int xx = axr[r] + tx;
                a[r] = *(const bfrag*)&halo[((dyr[r] + ty) * HALOW + xx) * 128
                                            + ((cc * 4 + kg) ^ (xx & 7)) * 8];
            }
#pragma unroll
            for (int r = 0; r < MR; ++r)
#pragma unroll
                for (int q = 0; q < NR; ++q)
                    acc[r][q] = __builtin_amdgcn_mfma_f32_16x16x32_bf16(a[r], bc[cc][q], acc[r][q], 0, 0, 0);
        }
        if (t < 8) {
#pragma unroll
            for (int cc = 0; cc < 4; ++cc)
#pragma unroll
                for (int q = 0; q < NR; ++q) bc[cc][q] = bn_[cc][q];
        }
    }

#pragma unroll
    for (int r = 0; r < MR; ++r) {
#pragma unroll
        for (int j = 0; j < 4; ++j) {
            int m = wm * (MR * 16) + r * 16 + kg * 4 + j;
            int pixl = pib + m;
            if (pixl >= HW) continue;
#pragma unroll
            for (int q = 0; q < NR; ++q) {
                int oc = wn * (NR * 16) + q * 16 + colc;
                float val = acc[r][q][j] + bias[oc];
                if constexpr (EPI == 0) {
                    val = fmaxf(val, 0.f);
                    int y = pixl / W, x = pixl - y * W;
                    ((u16*)Out)[((size_t)(n * Hp + y + 1) * Wq + x + 1) * 128 + oc] = f2bf(val);
                } else {
                    if (oc >= 18) val = 2.f / (1.f + expf(-val));
                    ((float*)Out)[((size_t)n * HW + pixl) * 32 + oc] = val;
                }
            }
        }
    }
}

// =====================================================================
// Fused deformable conv v7b — R14's verified deform7 (43.1 µs: 3-tap
// groups, B double-buffered in registers, 7 barriers, 2 blocks/CU)
// with the single change: bf16 T output (R15-verified).
// =====================================================================
__global__ __launch_bounds__(512, 4)
void deform7_k(const u16* __restrict__ Hb, const u16* __restrict__ Xp,
               const float* __restrict__ OM, const u16* __restrict__ Wp,
               const float* __restrict__ biasC, u16* __restrict__ T,
               int H, int W, int tw, int th)
{
    __shared__ __align__(16) u16 halo[96 * 16 * 8];    // 24576 B (8 rows x 12 cols)
    __shared__ __align__(16) u16 As3[3 * 32 * 128];    // 24576 B
    __shared__ __align__(16) float oml[27 * 32];       // 3456 B, [feature][pix]

    const int Hp = H + 2, Wq = W + 2, HW = H * W;
    const int tid = threadIdx.x, lane = tid & 63, wv = tid >> 6;
    const int wn = wv & 3, wm = wv >> 2;               // phase-2: wave = 16px x 32oc
    const int colc = lane & 15, kg = lane >> 4;
    int bt = blockIdx.x;
    int n = bt / (tw * th); int rt = bt - n * (tw * th);
    int ty0 = (rt / tw) * 4, tx0 = (rt - (rt / tw) * tw) * 8;
    const u16* Hbase = Hb + (size_t)n * Hp * Wq * 128;

    // ---- stage halo: 8 rows x 12 cols x 16 granules, slot-swizzled
#pragma unroll
    for (int c = 0; c < 3; ++c) {
        int g = c * 512 + tid;
        int s = g >> 4, u = g & 15;
        int row = s / 12, col = s - row * 12;
        int gy = min(max(ty0 - 2 + row, 0), H - 1);
        int gx = min(max(tx0 - 2 + col, 0), W - 1);
        int gr = u ^ (s & 15);
        gload16(Hbase + ((size_t)(gy + 1) * Wq + gx + 1) * 128 + gr * 8,
                &halo[(c * 512 + wv * 64) * 8]);
    }
    // ---- stage OM transposed: oml[f][p] (27 x 32)
    for (int e = tid; e < 27 * 32; e += 512) {
        int f = e >> 5, p = e & 31;
        int yy = min(ty0 + (p >> 3), H - 1), xx = min(tx0 + (p & 7), W - 1);
        oml[e] = OM[((size_t)n * HW + yy * W + xx) * 32 + f];
    }
    __syncthreads();

    // phase-1 thread role: (granule g0, pixel m0)
    const int g0 = tid & 15, m0 = (tid >> 4) & 31;
    const int cy1 = min(ty0 + (m0 >> 3), H - 1), cx1 = min(tx0 + (m0 & 7), W - 1);
    const int dslot = (g0 ^ (m0 & 7)) * 8;

    // phase-2 thread role
    const int m = wm * 16 + colc;
    const int cyp = min(ty0 + (m >> 3), H - 1), cxp = min(tx0 + (m & 7), W - 1);
    const size_t xoff = ((size_t)(n * Hp + cyp + 1) * Wq + cxp + 1) * 128;

    auto wfrag = [&](int tap, int cc, int q) -> const bfrag* {
        return (const bfrag*)(Wp + (size_t)tap * 16384
                              + ((cc * 8 + wn * 2 + q) * 64 + lane) * 8);
    };

    auto sample1 = [&](int t, int tb) {
        float dy = oml[(2 * t) * 32 + m0];
        float dx = oml[(2 * t + 1) * 32 + m0];
        float mm = oml[(18 + t) * 32 + m0];
        float pyf = (float)cy1 - 1.f + (float)(t / 3) + dy;
        float pxf = (float)cx1 - 1.f + (float)(t % 3) + dx;
        float fy = floorf(pyf), fx = floorf(pxf);
        int y0 = (int)fy, x0 = (int)fx;
        float wy = pyf - fy, wx = pxf - fx;
        bool y0v = (y0 >= 0) && (y0 < H), y1v = (y0 >= -1) && (y0 < H - 1);
        bool x0v = (x0 >= 0) && (x0 < W), x1v = (x0 >= -1) && (x0 < W - 1);
        int yc0 = min(max(y0, 0), H - 1), yc1 = min(max(y0 + 1, 0), H - 1);
        int xc0 = min(max(x0, 0), W - 1), xc1 = min(max(x0 + 1, 0), W - 1);
        float w00 = (1.f - wy) * (1.f - wx) * ((y0v && x0v) ? mm : 0.f);
        float w01 = (1.f - wy) * wx         * ((y0v && x1v) ? mm : 0.f);
        float w10 = wy * (1.f - wx)         * ((y1v && x0v) ? mm : 0.f);
        float w11 = wy * wx                 * ((y1v && x1v) ? mm : 0.f);
        int ry0 = yc0 - ty0 + 2, ry1 = yc1 - ty0 + 2;
        int rx0 = xc0 - tx0 + 2, rx1 = xc1 - tx0 + 2;
        bool allin = (unsigned)ry0 < 8u && (unsigned)ry1 < 8u
                  && (unsigned)rx0 < 12u && (unsigned)rx1 < 12u;
        bfrag c00, c01, c10, c11;
        if (allin) {
            int s00 = ry0 * 12 + rx0, s01 = ry0 * 12 + rx1;
            int s10 = ry1 * 12 + rx0, s11 = ry1 * 12 + rx1;
            c00 = *(const bfrag*)&halo[(s00 * 16 + (g0 ^ (s00 & 15))) * 8];
            c01 = *(const bfrag*)&halo[(s01 * 16 + (g0 ^ (s01 & 15))) * 8];
            c10 = *(const bfrag*)&halo[(s10 * 16 + (g0 ^ (s10 & 15))) * 8];
            c11 = *(const bfrag*)&halo[(s11 * 16 + (g0 ^ (s11 & 15))) * 8];
        } else {
            c00 = *(const bfrag*)(Hbase + ((size_t)(yc0 + 1) * Wq + xc0 + 1) * 128 + g0 * 8);
            c01 = *(const bfrag*)(Hbase + ((size_t)(yc0 + 1) * Wq + xc1 + 1) * 128 + g0 * 8);
            c10 = *(const bfrag*)(Hbase + ((size_t)(yc1 + 1) * Wq + xc0 + 1) * 128 + g0 * 8);
            c11 = *(const bfrag*)(Hbase + ((size_t)(yc1 + 1) * Wq + xc1 + 1) * 128 + g0 * 8);
        }
        bfrag o;
#pragma unroll
        for (int j = 0; j < 8; ++j) {
            float f = w00 * bf2f((u16)c00[j]) + w01 * bf2f((u16)c01[j])
                    + w10 * bf2f((u16)c10[j]) + w11 * bf2f((u16)c11[j]);
            o[j] = (short)f2bf(f);
        }
        *(bfrag*)&As3[tb * 4096 + m0 * 128 + dslot] = o;
    };

    bfrag bc[4][2];
#pragma unroll
    for (int cc = 0; cc < 4; ++cc)
#pragma unroll
        for (int q = 0; q < 2; ++q) bc[cc][q] = *wfrag(0, cc, q);

    facc acc[2];
    acc[0] = (facc){0.f, 0.f, 0.f, 0.f};
    acc[1] = (facc){0.f, 0.f, 0.f, 0.f};

#pragma unroll 1
    for (int tg = 0; tg < 3; ++tg) {
        sample1(tg * 3 + 0, 0);
        sample1(tg * 3 + 1, 1);
        sample1(tg * 3 + 2, 2);
        __syncthreads();
#pragma unroll
        for (int tb = 0; tb < 3; ++tb) {
            int t = tg * 3 + tb;
            bfrag bn_[4][2];
#pragma unroll
            for (int cc = 0; cc < 4; ++cc)
#pragma unroll
                for (int q = 0; q < 2; ++q) bn_[cc][q] = *wfrag(t + 1, cc, q);
            const u16* as = &As3[tb * 4096];
#pragma unroll
            for (int cc = 0; cc < 4; ++cc) {
                bfrag a = *(const bfrag*)&as[m * 128 + ((cc * 4 + kg) ^ (m & 7)) * 8];
#pragma unroll
                for (int q = 0; q < 2; ++q)
                    acc[q] = __builtin_amdgcn_mfma_f32_16x16x32_bf16(a, bc[cc][q], acc[q], 0, 0, 0);
            }
#pragma unroll
            for (int cc = 0; cc < 4; ++cc)
#pragma unroll
                for (int q = 0; q < 2; ++q) bc[cc][q] = bn_[cc][q];
        }
        __syncthreads();
    }

    // residual tap 9: bc holds tap-9 weights; A = x (padded NHWC)
#pragma unroll
    for (int cc = 0; cc < 4; ++cc) {
        bfrag a = *(const bfrag*)(Xp + xoff + (cc * 4 + kg) * 8);
#pragma unroll
        for (int q = 0; q < 2; ++q)
            acc[q] = __builtin_amdgcn_mfma_f32_16x16x32_bf16(a, bc[cc][q], acc[q], 0, 0, 0);
    }

    // epilogue -> bf16 T
#pragma unroll
    for (int j = 0; j < 4; ++j) {
        int mo = wm * 16 + kg * 4 + j;
        int y = ty0 + (mo >> 3), x = tx0 + (mo & 7);
        if (y >= H || x >= W) continue;
#pragma unroll
        for (int q = 0; q < 2; ++q) {
            int oc = wn * 32 + q * 16 + colc;
            T[((size_t)n * HW + y * W + x) * 128 + oc] =
                f2bf(fmaxf(acc[q][j] + biasC[oc], 0.f));
        }
    }
}

// ---- maxpool 2x2 s1 pad1: T bf16 [pix][128] -> padded NHWC bf16 / NCHW f32
template<int OUTMODE>
__global__ __launch_bounds__(256)
void pool_k(const u16* __restrict__ T, void* __restrict__ Out, int H, int W)
{
    const int HW = H * W, Ho = H + 1, Wo = W + 1;
    int tot = NN * Ho * Wo * 16;
    int idx = blockIdx.x * 256 + threadIdx.x;
    if (idx >= tot) return;
    int cg = idx & 15; int t = idx >> 4;
    int ox = t % Wo; t /= Wo; int oy = t % Ho; int n = t / Ho;

    float mx[8];
#pragma unroll
    for (int j = 0; j < 8; ++j) mx[j] = -INFINITY;
#pragma unroll
    for (int d = 0; d < 2; ++d) {
        int iy = oy - 1 + d;
        if (iy < 0 || iy >= H) continue;
#pragma unroll
        for (int e = 0; e < 2; ++e) {
            int ix = ox - 1 + e;
            if (ix < 0 || ix >= W) continue;
            bfrag v = *(const bfrag*)(T + ((size_t)(n * HW + iy * W + ix)) * 128 + cg * 8);
#pragma unroll
            for (int j = 0; j < 8; ++j) mx[j] = fmaxf(mx[j], bf2f((u16)v[j]));
        }
    }
    if constexpr (OUTMODE == 0) {
        int Hp2 = Ho + 2, Wp2 = Wo + 2;
        bfrag o;
#pragma unroll
        for (int j = 0; j < 8; ++j) o[j] = (short)f2bf(mx[j]);
        *(bfrag*)((u16*)Out + ((size_t)(n * Hp2 + oy + 1) * Wp2 + (ox + 1)) * 128 + cg * 8) = o;
    } else {
#pragma unroll
        for (int j = 0; j < 8; ++j) {
            int c = cg * 8 + j;
            ((float*)Out)[(((size_t)n * 128 + c) * Ho + oy) * Wo + ox] = mx[j];
        }
    }
}

// =====================================================================
// Merged prologue (unchanged, verified R14/R15).
// =====================================================================
__global__ __launch_bounds__(256)
void prolog_k(const float* __restrict__ x0,
              u16* __restrict__ Xp0, u16* __restrict__ Xp1,
              u16* __restrict__ Hp0, u16* __restrict__ Hp1,
              const float* __restrict__ w1, const float* __restrict__ b1,
              const float* __restrict__ g1, const float* __restrict__ be1,
              const float* __restrict__ m1, const float* __restrict__ v1,
              const float* __restrict__ w_off, const float* __restrict__ b_off,
              const float* __restrict__ w_mod, const float* __restrict__ b_mod,
              const float* __restrict__ w_def, const float* __restrict__ b_def,
              const float* __restrict__ g2, const float* __restrict__ be2,
              const float* __restrict__ m2, const float* __restrict__ v2,
              const float* __restrict__ w_ds, const float* __restrict__ b_ds,
              const float* __restrict__ g3, const float* __restrict__ be3,
              const float* __restrict__ m3, const float* __restrict__ v3,
              u16* __restrict__ Wb1p, u16* __restrict__ Wbomp, u16* __restrict__ Wbdp,
              float* __restrict__ bias1f, float* __restrict__ biasOM, float* __restrict__ biasC)
{
    const int P0 = 260, P1 = 264;
    const int B0 = NN * P0 * 16, B1 = NN * P1 * 16;
    int idx = blockIdx.x * 256 + threadIdx.x;
    bfrag z = (bfrag){0, 0, 0, 0, 0, 0, 0, 0};

    if (idx < 2 * B0) {
        u16* buf = idx < B0 ? Xp0 : Hp0;
        int e = idx < B0 ? idx : idx - B0;
        int gr = e & 15; int t = e >> 4;
        int b = t % P0; int n = t / P0;
        int y, x;
        if (b < 66)        { y = 0;  x = b; }
        else if (b < 132)  { y = 65; x = b - 66; }
        else { int r2 = b - 132; y = 1 + (r2 >> 1); x = (r2 & 1) ? 65 : 0; }
        *(bfrag*)(buf + ((size_t)(n * 66 + y) * 66 + x) * 128 + gr * 8) = z;
        return;
    }
    idx -= 2 * B0;
    if (idx < 2 * B1) {
        u16* buf = idx < B1 ? Xp1 : Hp1;
        int e = idx < B1 ? idx : idx - B1;
        int gr = e & 15; int t = e >> 4;
        int b = t % P1; int n = t / P1;
        int y, x;
        if (b < 67)        { y = 0;  x = b; }
        else if (b < 134)  { y = 66; x = b - 67; }
        else { int r2 = b - 134; y = 1 + (r2 >> 1); x = (r2 & 1) ? 66 : 0; }
        *(bfrag*)(buf + ((size_t)(n * 67 + y) * 67 + x) * 128 + gr * 8) = z;
        return;
    }
    idx -= 2 * B1;

    if (idx < NN * 64 * 64 * 16) {
        int cg = idx & 15; int t = idx >> 4;
        int x = t & 63; t >>= 6; int y = t & 63; int n = t >> 6;
        bfrag o;
#pragma unroll
        for (int j = 0; j < 8; ++j) {
            int c = cg * 8 + j;
            o[j] = (short)f2bf(x0[(((size_t)n * 128 + c) * 64 + y) * 64 + x]);
        }
        *(bfrag*)(Xp0 + ((size_t)(n * 66 + y + 1) * 66 + (x + 1)) * 128 + cg * 8) = o;
        return;
    }
    idx -= NN * 64 * 64 * 16;

    const int C1 = 9 * 4 * 8 * 512;   // 147456
    const int C2 = 9 * 4 * 2 * 512;   // 36864
    const int C3 = 10 * 4 * 8 * 512;  // 163840
    if (idx < 2 * C1) {
        int inst = idx / C1, e = idx - inst * C1;
        int j = e & 7, lane = (e >> 3) & 63, rest = e >> 9;
        int ob = rest & 7; rest >>= 3; int cc = rest & 3; int tap = rest >> 2;
        int oc = ob * 16 + (lane & 15), c = cc * 32 + (lane >> 4) * 8 + j;
        float sc = g1[inst * 128 + oc] * rsqrtf(v1[inst * 128 + oc] + 1e-5f);
        Wb1p[idx] = f2bf(sc * w1[(((size_t)inst * 128 + oc) * 128 + c) * 9 + tap]);
        return;
    }
    idx -= 2 * C1;
    if (idx < 2 * C2) {
        int inst = idx / C2, e = idx - inst * C2;
        int j = e & 7, lane = (e >> 3) & 63, rest = e >> 9;
        int ob = rest & 1; rest >>= 1; int cc = rest & 3; int tap = rest >> 2;
        int oc = ob * 16 + (lane & 15), c = cc * 32 + (lane >> 4) * 8 + j;
        float v = 0.f;
        if (oc < 18)      v = w_off[(((size_t)inst * 18 + oc) * 128 + c) * 9 + tap];
        else if (oc < 27) v = w_mod[(((size_t)inst * 9 + (oc - 18)) * 128 + c) * 9 + tap];
        Wbomp[inst * C2 + e] = f2bf(v);
        return;
    }
    idx -= 2 * C2;
    if (idx < 2 * C3) {
        int inst = idx / C3, e = idx - inst * C3;
        int j = e & 7, lane = (e >> 3) & 63, rest = e >> 9;
        int ob = rest & 7; rest >>= 3; int cc = rest & 3; int tap = rest >> 2;
        int oc = ob * 16 + (lane & 15), c = cc * 32 + (lane >> 4) * 8 + j;
        float val;
        if (tap < 9) {
            float sc2 = g2[inst * 128 + oc] * rsqrtf(v2[inst * 128 + oc] + 1e-5f);
            val = sc2 * w_def[(((size_t)inst * 128 + oc) * 128 + c) * 9 + tap];
        } else {
            float sc3 = g3[inst * 128 + oc] * rsqrtf(v3[inst * 128 + oc] + 1e-5f);
            val = sc3 * w_ds[((size_t)inst * 128 + oc) * 128 + c];
        }
        Wbdp[inst * C3 + e] = f2bf(val);
        return;
    }
    idx -= 2 * C3;
    if (idx < 2 * 288) {
        int inst = idx / 288, r = idx - inst * 288;
        if (r < 128) {
            int oc = r, o = inst * 128 + oc;
            float sc = g1[o] * rsqrtf(v1[o] + 1e-5f);
            bias1f[o] = sc * b1[o] + be1[o] - m1[o] * sc;
        } else if (r < 160) {
            int oc = r - 128;
            float v = 0.f;
            if (oc < 18)      v = b_off[inst * 18 + oc];
            else if (oc < 27) v = b_mod[inst * 9 + (oc - 18)];
            biasOM[inst * 32 + oc] = v;
        } else {
            int oc = r - 160, o = inst * 128 + oc;
            float sc2 = g2[o] * rsqrtf(v2[o] + 1e-5f);
            float sc3 = g3[o] * rsqrtf(v3[o] + 1e-5f);
            biasC[o] = sc2 * b_def[o] + (be2[o] - m2[o] * sc2)
                     + sc3 * b_ds[o] + (be3[o] - m3[o] * sc3);
        }
    }
}

extern "C" void kernel_launch(void* const* d_in, const int* in_sizes, int n_in,
                              void* d_out, int out_size, void* d_ws, size_t ws_size,
                              hipStream_t stream)
{
    const float* x0    = (const float*)d_in[0];
    const float* w1    = (const float*)d_in[1];
    const float* b1    = (const float*)d_in[2];
    const float* g1    = (const float*)d_in[3];
    const float* be1   = (const float*)d_in[4];
    const float* m1    = (const float*)d_in[5];
    const float* v1    = (const float*)d_in[6];
    const float* w_off = (const float*)d_in[7];
    const float* b_off = (const float*)d_in[8];
    const float* w_mod = (const float*)d_in[9];
    const float* b_mod = (const float*)d_in[10];
    const float* w_def = (const float*)d_in[11];
    const float* b_def = (const float*)d_in[12];
    const float* g2    = (const float*)d_in[13];
    const float* be2   = (const float*)d_in[14];
    const float* m2    = (const float*)d_in[15];
    const float* v2    = (const float*)d_in[16];
    const float* w_ds  = (const float*)d_in[17];
    const float* b_ds  = (const float*)d_in[18];
    const float* g3    = (const float*)d_in[19];
    const float* be3   = (const float*)d_in[20];
    const float* m3    = (const float*)d_in[21];
    const float* v3    = (const float*)d_in[22];

    const int C1 = 147456, C2 = 36864, C3 = 163840;
    char* wsp = (char*)d_ws;
    auto alloc = [&](size_t bytes) { char* r = wsp; wsp += (bytes + 255) & ~(size_t)255; return r; };
    const size_t szX0 = (size_t)NN * 66 * 66 * 128 * 2;
    const size_t szX1 = (size_t)NN * 67 * 67 * 128 * 2;
    u16*   Xpad0  = (u16*)alloc(szX0);
    u16*   Xpad1  = (u16*)alloc(szX1);
    u16*   Hpad0  = (u16*)alloc(szX0);
    u16*   Hpad1  = (u16*)alloc(szX1);
    float* OFFMSK = (float*)alloc((size_t)16900 * 32 * 4);
    u16*   T      = (u16*)alloc((size_t)16900 * 128 * 2);
    u16*   Wb1p   = (u16*)alloc((size_t)2 * C1 * 2);
    u16*   Wbomp  = (u16*)alloc((size_t)2 * C2 * 2);
    u16*   Wbdp   = (u16*)alloc((size_t)2 * C3 * 2);
    float* bias1f = (float*)alloc(2 * 128 * 4);
    float* biasOM = (float*)alloc(2 * 32 * 4);
    float* biasC  = (float*)alloc(2 * 128 * 4);

    // ---- merged prologue: border zero + layout + weight packing ---------
    const int B0 = NN * 260 * 16, B1 = NN * 264 * 16;
    int ptot = 2 * B0 + 2 * B1 + NN * 64 * 64 * 16 + 2 * C1 + 2 * C2 + 2 * C3 + 2 * 288;
    prolog_k<<<(ptot + 255) / 256, 256, 0, stream>>>(
        x0, Xpad0, Xpad1, Hpad0, Hpad1,
        w1, b1, g1, be1, m1, v1, w_off, b_off, w_mod, b_mod, w_def, b_def,
        g2, be2, m2, v2, w_ds, b_ds, g3, be3, m3, v3,
        Wb1p, Wbomp, Wbdp, bias1f, biasOM, biasC);

    const u16* curX = Xpad0;
    for (int i = 0; i < 2; ++i) {
        int H = 64 + i, W = 64 + i;
        int HW = H * W;
        int npb = (HW + 63) / 64;
        int grid = NN * npb;
        u16* Hpad = (i == 0) ? Hpad0 : Hpad1;

        // h = relu(bn1(conv3x3(x)))
        gconv_h<2, 4, 2, 2, 8, 0><<<grid, 512, 0, stream>>>(
            curX, Wb1p + (size_t)i * C1, bias1f + i * 128, Hpad, H, W, npb);
        // off(18) + msk(9, 2*sigmoid) -> OFFMSK [pix][32]
        gconv_h<4, 2, 1, 1, 2, 1><<<grid, 512, 0, stream>>>(
            Hpad, Wbomp + (size_t)i * C2, biasOM + i * 32, OFFMSK, H, W, npb);
        // fused deformable conv + residual + bn2/bn3 + relu (3-tap groups)
        int tw = (W + 7) / 8, th = (H + 3) / 4;
        deform7_k<<<NN * tw * th, 512, 0, stream>>>(
            Hpad, curX, OFFMSK, Wbdp + (size_t)i * C3, biasC + i * 128, T, H, W, tw, th);
        // maxpool
        if (i == 0) {
            pool_k<0><<<(NN * 65 * 65 * 16 + 255) / 256, 256, 0, stream>>>(T, Xpad1, H, W);
        } else {
            pool_k<1><<<(NN * 66 * 66 * 16 + 255) / 256, 256, 0, stream>>>(T, d_out, H, W);
        }
        curX = Xpad1;
    }
}

// Round 17
// 128.759 us; speedup vs baseline: 1.0460x; 1.0460x over previous
//
#include <hip/hip_runtime.h>
#include <math.h>

constexpr int NN = 4;    // batch
constexpr int CC = 128;  // channels

typedef unsigned short u16;
typedef short bfrag __attribute__((ext_vector_type(8)));   // 8 bf16
typedef float facc  __attribute__((ext_vector_type(4)));   // 4 f32 acc

__device__ __forceinline__ float bf2f(u16 v) {
    unsigned u = ((unsigned)v) << 16; float f; __builtin_memcpy(&f, &u, 4); return f;
}
__device__ __forceinline__ u16 f2bf(float f) {
    unsigned u; __builtin_memcpy(&u, &f, 4);
    unsigned r = u + 0x7FFFu + ((u >> 16) & 1u);
    return (u16)(r >> 16);
}

typedef const __attribute__((address_space(1))) unsigned int gu32;
typedef __attribute__((address_space(3))) unsigned int lu32;
__device__ __forceinline__ void gload16(const u16* g, u16* l) {
    __builtin_amdgcn_global_load_lds((gu32*)g, (lu32*)l, 16, 0, 0);
}

// =====================================================================
// Halo-LDS 3x3 conv GEMM (unchanged, verified R5-R16).
// =====================================================================
template<int WM, int WN, int MR, int NR, int NOB, int EPI>
__global__ __launch_bounds__(512)
void gconv_h(const u16* __restrict__ A, const u16* __restrict__ Wp,
             const float* __restrict__ bias, void* __restrict__ Out,
             int H, int W, int npb)
{
    constexpr int HALOW = 68;
    __shared__ __align__(16) u16 halo[4 * HALOW * 128];    // 69632 B

    const int Hp = H + 2, Wq = W + 2, HW = H * W;
    const int tid = threadIdx.x, lane = tid & 63, wv = tid >> 6;
    const int wn = wv % WN, wm = wv / WN;
    const int colc = lane & 15, kg = lane >> 4;
    const int n = blockIdx.x / npb;
    const int pib = (blockIdx.x - n * npb) * 64;
    const int ymin = pib / W;

    {
        const u16* Abase = A + (size_t)n * Hp * Wq * 128;
        for (int c = wv; c < 4 * HALOW / 4; c += 8) {
            int o = c * 512 + lane * 8;
            int r = o / (HALOW * 128);
            int e = o - r * (HALOW * 128);
            int x = e >> 7;
            int g = (e >> 3) & 15;
            int xs = x < Wq ? x : Wq - 1;
            int pr = ymin + r; if (pr > Hp - 1) pr = Hp - 1;
            const u16* src = Abase + ((size_t)pr * Wq + xs) * 128 + (g ^ (x & 7)) * 8;
            gload16(src, &halo[c * 512]);
        }
    }
    __syncthreads();

    int dyr[MR], axr[MR];
#pragma unroll
    for (int r = 0; r < MR; ++r) {
        int m = wm * (MR * 16) + r * 16 + colc;
        int pixl = pib + m; if (pixl > HW - 1) pixl = HW - 1;
        int y = pixl / W;
        dyr[r] = y - ymin; axr[r] = pixl - y * W;
    }

    auto wfrag = [&](int tap, int cc, int q) -> const bfrag* {
        return (const bfrag*)(Wp + (size_t)tap * (NOB * 2048)
                              + ((cc * NOB + wn * NR + q) * 64 + lane) * 8);
    };

    bfrag bc[4][NR];
#pragma unroll
    for (int cc = 0; cc < 4; ++cc)
#pragma unroll
        for (int q = 0; q < NR; ++q) bc[cc][q] = *wfrag(0, cc, q);

    facc acc[MR][NR];
#pragma unroll
    for (int r = 0; r < MR; ++r)
#pragma unroll
        for (int q = 0; q < NR; ++q) acc[r][q] = (facc){0.f, 0.f, 0.f, 0.f};

#pragma unroll 1
    for (int t = 0; t < 9; ++t) {
        int ty = t / 3, tx = t - ty * 3;
        bfrag bn_[4][NR];
        if (t < 8) {
#pragma unroll
            for (int cc = 0; cc < 4; ++cc)
#pragma unroll
                for (int q = 0; q < NR; ++q) bn_[cc][q] = *wfrag(t + 1, cc, q);
        }
#pragma unroll
        for (int cc = 0; cc < 4; ++cc) {
            bfrag a[MR];
#pragma unroll
            for (int r = 0; r < MR; ++r) {
                int xx = axr[r] + tx;
                a[r] = *(const bfrag*)&halo[((dyr[r] + ty) * HALOW + xx) * 128
                                            + ((cc * 4 + kg) ^ (xx & 7)) * 8];
            }
#pragma unroll
            for (int r = 0; r < MR; ++r)
#pragma unroll
                for (int q = 0; q < NR; ++q)
                    acc[r][q] = __builtin_amdgcn_mfma_f32_16x16x32_bf16(a[r], bc[cc][q], acc[r][q], 0, 0, 0);
        }
        if (t < 8) {
#pragma unroll
            for (int cc = 0; cc < 4; ++cc)
#pragma unroll
                for (int q = 0; q < NR; ++q) bc[cc][q] = bn_[cc][q];
        }
    }

#pragma unroll
    for (int r = 0; r < MR; ++r) {
#pragma unroll
        for (int j = 0; j < 4; ++j) {
            int m = wm * (MR * 16) + r * 16 + kg * 4 + j;
            int pixl = pib + m;
            if (pixl >= HW) continue;
#pragma unroll
            for (int q = 0; q < NR; ++q) {
                int oc = wn * (NR * 16) + q * 16 + colc;
                float val = acc[r][q][j] + bias[oc];
                if constexpr (EPI == 0) {
                    val = fmaxf(val, 0.f);
                    int y = pixl / W, x = pixl - y * W;
                    ((u16*)Out)[((size_t)(n * Hp + y + 1) * Wq + x + 1) * 128 + oc] = f2bf(val);
                } else {
                    if (oc >= 18) val = 2.f / (1.f + expf(-val));
                    ((float*)Out)[((size_t)n * HW + pixl) * 32 + oc] = val;
                }
            }
        }
    }
}

// =====================================================================
// Fused deformable conv v9 — quarter-tile for grid occupancy.
// 4x4 px tile, 256 threads (4 waves). Same verified shape as deform7:
// slot-swizzled halo (8x8), 3-tap As3 groups, B double-buffered in
// registers, 7 barriers, bf16 T. Grid = NN*16*16 = 1024 blocks ->
// 4 blocks/CU (16 waves/CU), double R16's resident waves.
// LDS 30.4 KB. Out-of-window corners (rare) fall back to global.
// =====================================================================
__global__ __launch_bounds__(256, 4)
void deform9_k(const u16* __restrict__ Hb, const u16* __restrict__ Xp,
               const float* __restrict__ OM, const u16* __restrict__ Wp,
               const float* __restrict__ biasC, u16* __restrict__ T,
               int H, int W, int tw, int th)
{
    __shared__ __align__(16) u16 halo[64 * 16 * 8];    // 16384 B (8 rows x 8 cols)
    __shared__ __align__(16) u16 As3[3 * 16 * 128];    // 12288 B
    __shared__ __align__(16) float oml[27 * 16];       // 1728 B, [feature][pix]

    const int Hp = H + 2, Wq = W + 2, HW = H * W;
    const int tid = threadIdx.x, lane = tid & 63, wv = tid >> 6;
    const int wn = wv;                                 // wave = 16px x 32oc
    const int colc = lane & 15, kg = lane >> 4;
    int bt = blockIdx.x;
    int n = bt / (tw * th); int rt = bt - n * (tw * th);
    int ty0 = (rt / tw) * 4, tx0 = (rt - (rt / tw) * tw) * 4;
    const u16* Hbase = Hb + (size_t)n * Hp * Wq * 128;

    // ---- stage halo: 8 rows x 8 cols x 16 granules = 1024, slot-swizzled
#pragma unroll
    for (int c = 0; c < 4; ++c) {
        int g = c * 256 + tid;
        int s = g >> 4, u = g & 15;
        int row = s >> 3, col = s & 7;
        int gy = min(max(ty0 - 2 + row, 0), H - 1);
        int gx = min(max(tx0 - 2 + col, 0), W - 1);
        int gr = u ^ (s & 15);
        gload16(Hbase + ((size_t)(gy + 1) * Wq + gx + 1) * 128 + gr * 8,
                &halo[(c * 256 + wv * 64) * 8]);
    }
    // ---- stage OM transposed: oml[f][p] (27 x 16)
    for (int e = tid; e < 27 * 16; e += 256) {
        int f = e >> 4, p = e & 15;
        int yy = min(ty0 + (p >> 2), H - 1), xx = min(tx0 + (p & 3), W - 1);
        oml[e] = OM[((size_t)n * HW + yy * W + xx) * 32 + f];
    }
    __syncthreads();

    // phase-1 thread role: (granule g0, pixel m0)
    const int g0 = tid & 15, m0 = tid >> 4;            // m0 in [0,16)
    const int cy1 = min(ty0 + (m0 >> 2), H - 1), cx1 = min(tx0 + (m0 & 3), W - 1);
    const int dslot = (g0 ^ (m0 & 7)) * 8;

    // phase-2 thread role: pixel = colc
    const int m = colc;
    const int cyp = min(ty0 + (m >> 2), H - 1), cxp = min(tx0 + (m & 3), W - 1);
    const size_t xoff = ((size_t)(n * Hp + cyp + 1) * Wq + cxp + 1) * 128;

    auto wfrag = [&](int tap, int cc, int q) -> const bfrag* {
        return (const bfrag*)(Wp + (size_t)tap * 16384
                              + ((cc * 8 + wn * 2 + q) * 64 + lane) * 8);
    };

    auto sample1 = [&](int t, int tb) {
        float dy = oml[(2 * t) * 16 + m0];
        float dx = oml[(2 * t + 1) * 16 + m0];
        float mm = oml[(18 + t) * 16 + m0];
        float pyf = (float)cy1 - 1.f + (float)(t / 3) + dy;
        float pxf = (float)cx1 - 1.f + (float)(t % 3) + dx;
        float fy = floorf(pyf), fx = floorf(pxf);
        int y0 = (int)fy, x0 = (int)fx;
        float wy = pyf - fy, wx = pxf - fx;
        bool y0v = (y0 >= 0) && (y0 < H), y1v = (y0 >= -1) && (y0 < H - 1);
        bool x0v = (x0 >= 0) && (x0 < W), x1v = (x0 >= -1) && (x0 < W - 1);
        int yc0 = min(max(y0, 0), H - 1), yc1 = min(max(y0 + 1, 0), H - 1);
        int xc0 = min(max(x0, 0), W - 1), xc1 = min(max(x0 + 1, 0), W - 1);
        float w00 = (1.f - wy) * (1.f - wx) * ((y0v && x0v) ? mm : 0.f);
        float w01 = (1.f - wy) * wx         * ((y0v && x1v) ? mm : 0.f);
        float w10 = wy * (1.f - wx)         * ((y1v && x0v) ? mm : 0.f);
        float w11 = wy * wx                 * ((y1v && x1v) ? mm : 0.f);
        int ry0 = yc0 - ty0 + 2, ry1 = yc1 - ty0 + 2;
        int rx0 = xc0 - tx0 + 2, rx1 = xc1 - tx0 + 2;
        bool allin = (unsigned)ry0 < 8u && (unsigned)ry1 < 8u
                  && (unsigned)rx0 < 8u && (unsigned)rx1 < 8u;
        bfrag c00, c01, c10, c11;
        if (allin) {
            int s00 = ry0 * 8 + rx0, s01 = ry0 * 8 + rx1;
            int s10 = ry1 * 8 + rx0, s11 = ry1 * 8 + rx1;
            c00 = *(const bfrag*)&halo[(s00 * 16 + (g0 ^ (s00 & 15))) * 8];
            c01 = *(const bfrag*)&halo[(s01 * 16 + (g0 ^ (s01 & 15))) * 8];
            c10 = *(const bfrag*)&halo[(s10 * 16 + (g0 ^ (s10 & 15))) * 8];
            c11 = *(const bfrag*)&halo[(s11 * 16 + (g0 ^ (s11 & 15))) * 8];
        } else {
            c00 = *(const bfrag*)(Hbase + ((size_t)(yc0 + 1) * Wq + xc0 + 1) * 128 + g0 * 8);
            c01 = *(const bfrag*)(Hbase + ((size_t)(yc0 + 1) * Wq + xc1 + 1) * 128 + g0 * 8);
            c10 = *(const bfrag*)(Hbase + ((size_t)(yc1 + 1) * Wq + xc0 + 1) * 128 + g0 * 8);
            c11 = *(const bfrag*)(Hbase + ((size_t)(yc1 + 1) * Wq + xc1 + 1) * 128 + g0 * 8);
        }
        bfrag o;
#pragma unroll
        for (int j = 0; j < 8; ++j) {
            float f = w00 * bf2f((u16)c00[j]) + w01 * bf2f((u16)c01[j])
                    + w10 * bf2f((u16)c10[j]) + w11 * bf2f((u16)c11[j]);
            o[j] = (short)f2bf(f);
        }
        *(bfrag*)&As3[tb * 2048 + m0 * 128 + dslot] = o;
    };

    bfrag bc[4][2];
#pragma unroll
    for (int cc = 0; cc < 4; ++cc)
#pragma unroll
        for (int q = 0; q < 2; ++q) bc[cc][q] = *wfrag(0, cc, q);

    facc acc[2];
    acc[0] = (facc){0.f, 0.f, 0.f, 0.f};
    acc[1] = (facc){0.f, 0.f, 0.f, 0.f};

#pragma unroll 1
    for (int tg = 0; tg < 3; ++tg) {
        sample1(tg * 3 + 0, 0);
        sample1(tg * 3 + 1, 1);
        sample1(tg * 3 + 2, 2);
        __syncthreads();
#pragma unroll
        for (int tb = 0; tb < 3; ++tb) {
            int t = tg * 3 + tb;
            bfrag bn_[4][2];
#pragma unroll
            for (int cc = 0; cc < 4; ++cc)
#pragma unroll
                for (int q = 0; q < 2; ++q) bn_[cc][q] = *wfrag(t + 1, cc, q);
            const u16* as = &As3[tb * 2048];
#pragma unroll
            for (int cc = 0; cc < 4; ++cc) {
                bfrag a = *(const bfrag*)&as[m * 128 + ((cc * 4 + kg) ^ (m & 7)) * 8];
#pragma unroll
                for (int q = 0; q < 2; ++q)
                    acc[q] = __builtin_amdgcn_mfma_f32_16x16x32_bf16(a, bc[cc][q], acc[q], 0, 0, 0);
            }
#pragma unroll
            for (int cc = 0; cc < 4; ++cc)
#pragma unroll
                for (int q = 0; q < 2; ++q) bc[cc][q] = bn_[cc][q];
        }
        __syncthreads();
    }

    // residual tap 9: bc holds tap-9 weights; A = x (padded NHWC)
#pragma unroll
    for (int cc = 0; cc < 4; ++cc) {
        bfrag a = *(const bfrag*)(Xp + xoff + (cc * 4 + kg) * 8);
#pragma unroll
        for (int q = 0; q < 2; ++q)
            acc[q] = __builtin_amdgcn_mfma_f32_16x16x32_bf16(a, bc[cc][q], acc[q], 0, 0, 0);
    }

    // epilogue -> bf16 T
#pragma unroll
    for (int j = 0; j < 4; ++j) {
        int mo = kg * 4 + j;
        int y = ty0 + (mo >> 2), x = tx0 + (mo & 3);
        if (y >= H || x >= W) continue;
#pragma unroll
        for (int q = 0; q < 2; ++q) {
            int oc = wn * 32 + q * 16 + colc;
            T[((size_t)n * HW + y * W + x) * 128 + oc] =
                f2bf(fmaxf(acc[q][j] + biasC[oc], 0.f));
        }
    }
}

// ---- maxpool 2x2 s1 pad1: T bf16 [pix][128] -> padded NHWC bf16 / NCHW f32
template<int OUTMODE>
__global__ __launch_bounds__(256)
void pool_k(const u16* __restrict__ T, void* __restrict__ Out, int H, int W)
{
    const int HW = H * W, Ho = H + 1, Wo = W + 1;
    int tot = NN * Ho * Wo * 16;
    int idx = blockIdx.x * 256 + threadIdx.x;
    if (idx >= tot) return;
    int cg = idx & 15; int t = idx >> 4;
    int ox = t % Wo; t /= Wo; int oy = t % Ho; int n = t / Ho;

    float mx[8];
#pragma unroll
    for (int j = 0; j < 8; ++j) mx[j] = -INFINITY;
#pragma unroll
    for (int d = 0; d < 2; ++d) {
        int iy = oy - 1 + d;
        if (iy < 0 || iy >= H) continue;
#pragma unroll
        for (int e = 0; e < 2; ++e) {
            int ix = ox - 1 + e;
            if (ix < 0 || ix >= W) continue;
            bfrag v = *(const bfrag*)(T + ((size_t)(n * HW + iy * W + ix)) * 128 + cg * 8);
#pragma unroll
            for (int j = 0; j < 8; ++j) mx[j] = fmaxf(mx[j], bf2f((u16)v[j]));
        }
    }
    if constexpr (OUTMODE == 0) {
        int Hp2 = Ho + 2, Wp2 = Wo + 2;
        bfrag o;
#pragma unroll
        for (int j = 0; j < 8; ++j) o[j] = (short)f2bf(mx[j]);
        *(bfrag*)((u16*)Out + ((size_t)(n * Hp2 + oy + 1) * Wp2 + (ox + 1)) * 128 + cg * 8) = o;
    } else {
#pragma unroll
        for (int j = 0; j < 8; ++j) {
            int c = cg * 8 + j;
            ((float*)Out)[(((size_t)n * 128 + c) * Ho + oy) * Wo + ox] = mx[j];
        }
    }
}

// =====================================================================
// Merged prologue (unchanged, verified R14-R16).
// =====================================================================
__global__ __launch_bounds__(256)
void prolog_k(const float* __restrict__ x0,
              u16* __restrict__ Xp0, u16* __restrict__ Xp1,
              u16* __restrict__ Hp0, u16* __restrict__ Hp1,
              const float* __restrict__ w1, const float* __restrict__ b1,
              const float* __restrict__ g1, const float* __restrict__ be1,
              const float* __restrict__ m1, const float* __restrict__ v1,
              const float* __restrict__ w_off, const float* __restrict__ b_off,
              const float* __restrict__ w_mod, const float* __restrict__ b_mod,
              const float* __restrict__ w_def, const float* __restrict__ b_def,
              const float* __restrict__ g2, const float* __restrict__ be2,
              const float* __restrict__ m2, const float* __restrict__ v2,
              const float* __restrict__ w_ds, const float* __restrict__ b_ds,
              const float* __restrict__ g3, const float* __restrict__ be3,
              const float* __restrict__ m3, const float* __restrict__ v3,
              u16* __restrict__ Wb1p, u16* __restrict__ Wbomp, u16* __restrict__ Wbdp,
              float* __restrict__ bias1f, float* __restrict__ biasOM, float* __restrict__ biasC)
{
    const int P0 = 260, P1 = 264;
    const int B0 = NN * P0 * 16, B1 = NN * P1 * 16;
    int idx = blockIdx.x * 256 + threadIdx.x;
    bfrag z = (bfrag){0, 0, 0, 0, 0, 0, 0, 0};

    if (idx < 2 * B0) {
        u16* buf = idx < B0 ? Xp0 : Hp0;
        int e = idx < B0 ? idx : idx - B0;
        int gr = e & 15; int t = e >> 4;
        int b = t % P0; int n = t / P0;
        int y, x;
        if (b < 66)        { y = 0;  x = b; }
        else if (b < 132)  { y = 65; x = b - 66; }
        else { int r2 = b - 132; y = 1 + (r2 >> 1); x = (r2 & 1) ? 65 : 0; }
        *(bfrag*)(buf + ((size_t)(n * 66 + y) * 66 + x) * 128 + gr * 8) = z;
        return;
    }
    idx -= 2 * B0;
    if (idx < 2 * B1) {
        u16* buf = idx < B1 ? Xp1 : Hp1;
        int e = idx < B1 ? idx : idx - B1;
        int gr = e & 15; int t = e >> 4;
        int b = t % P1; int n = t / P1;
        int y, x;
        if (b < 67)        { y = 0;  x = b; }
        else if (b < 134)  { y = 66; x = b - 67; }
        else { int r2 = b - 134; y = 1 + (r2 >> 1); x = (r2 & 1) ? 66 : 0; }
        *(bfrag*)(buf + ((size_t)(n * 67 + y) * 67 + x) * 128 + gr * 8) = z;
        return;
    }
    idx -= 2 * B1;

    if (idx < NN * 64 * 64 * 16) {
        int cg = idx & 15; int t = idx >> 4;
        int x = t & 63; t >>= 6; int y = t & 63; int n = t >> 6;
        bfrag o;
#pragma unroll
        for (int j = 0; j < 8; ++j) {
            int c = cg * 8 + j;
            o[j] = (short)f2bf(x0[(((size_t)n * 128 + c) * 64 + y) * 64 + x]);
        }
        *(bfrag*)(Xp0 + ((size_t)(n * 66 + y + 1) * 66 + (x + 1)) * 128 + cg * 8) = o;
        return;
    }
    idx -= NN * 64 * 64 * 16;

    const int C1 = 9 * 4 * 8 * 512;   // 147456
    const int C2 = 9 * 4 * 2 * 512;   // 36864
    const int C3 = 10 * 4 * 8 * 512;  // 163840
    if (idx < 2 * C1) {
        int inst = idx / C1, e = idx - inst * C1;
        int j = e & 7, lane = (e >> 3) & 63, rest = e >> 9;
        int ob = rest & 7; rest >>= 3; int cc = rest & 3; int tap = rest >> 2;
        int oc = ob * 16 + (lane & 15), c = cc * 32 + (lane >> 4) * 8 + j;
        float sc = g1[inst * 128 + oc] * rsqrtf(v1[inst * 128 + oc] + 1e-5f);
        Wb1p[idx] = f2bf(sc * w1[(((size_t)inst * 128 + oc) * 128 + c) * 9 + tap]);
        return;
    }
    idx -= 2 * C1;
    if (idx < 2 * C2) {
        int inst = idx / C2, e = idx - inst * C2;
        int j = e & 7, lane = (e >> 3) & 63, rest = e >> 9;
        int ob = rest & 1; rest >>= 1; int cc = rest & 3; int tap = rest >> 2;
        int oc = ob * 16 + (lane & 15), c = cc * 32 + (lane >> 4) * 8 + j;
        float v = 0.f;
        if (oc < 18)      v = w_off[(((size_t)inst * 18 + oc) * 128 + c) * 9 + tap];
        else if (oc < 27) v = w_mod[(((size_t)inst * 9 + (oc - 18)) * 128 + c) * 9 + tap];
        Wbomp[inst * C2 + e] = f2bf(v);
        return;
    }
    idx -= 2 * C2;
    if (idx < 2 * C3) {
        int inst = idx / C3, e = idx - inst * C3;
        int j = e & 7, lane = (e >> 3) & 63, rest = e >> 9;
        int ob = rest & 7; rest >>= 3; int cc = rest & 3; int tap = rest >> 2;
        int oc = ob * 16 + (lane & 15), c = cc * 32 + (lane >> 4) * 8 + j;
        float val;
        if (tap < 9) {
            float sc2 = g2[inst * 128 + oc] * rsqrtf(v2[inst * 128 + oc] + 1e-5f);
            val = sc2 * w_def[(((size_t)inst * 128 + oc) * 128 + c) * 9 + tap];
        } else {
            float sc3 = g3[inst * 128 + oc] * rsqrtf(v3[inst * 128 + oc] + 1e-5f);
            val = sc3 * w_ds[((size_t)inst * 128 + oc) * 128 + c];
        }
        Wbdp[inst * C3 + e] = f2bf(val);
        return;
    }
    idx -= 2 * C3;
    if (idx < 2 * 288) {
        int inst = idx / 288, r = idx - inst * 288;
        if (r < 128) {
            int oc = r, o = inst * 128 + oc;
            float sc = g1[o] * rsqrtf(v1[o] + 1e-5f);
            bias1f[o] = sc * b1[o] + be1[o] - m1[o] * sc;
        } else if (r < 160) {
            int oc = r - 128;
            float v = 0.f;
            if (oc < 18)      v = b_off[inst * 18 + oc];
            else if (oc < 27) v = b_mod[inst * 9 + (oc - 18)];
            biasOM[inst * 32 + oc] = v;
        } else {
            int oc = r - 160, o = inst * 128 + oc;
            float sc2 = g2[o] * rsqrtf(v2[o] + 1e-5f);
            float sc3 = g3[o] * rsqrtf(v3[o] + 1e-5f);
            biasC[o] = sc2 * b_def[o] + (be2[o] - m2[o] * sc2)
                     + sc3 * b_ds[o] + (be3[o] - m3[o] * sc3);
        }
    }
}

extern "C" void kernel_launch(void* const* d_in, const int* in_sizes, int n_in,
                              void* d_out, int out_size, void* d_ws, size_t ws_size,
                              hipStream_t stream)
{
    const float* x0    = (const float*)d_in[0];
    const float* w1    = (const float*)d_in[1];
    const float* b1    = (const float*)d_in[2];
    const float* g1    = (const float*)d_in[3];
    const float* be1   = (const float*)d_in[4];
    const float* m1    = (const float*)d_in[5];
    const float* v1    = (const float*)d_in[6];
    const float* w_off = (const float*)d_in[7];
    const float* b_off = (const float*)d_in[8];
    const float* w_mod = (const float*)d_in[9];
    const float* b_mod = (const float*)d_in[10];
    const float* w_def = (const float*)d_in[11];
    const float* b_def = (const float*)d_in[12];
    const float* g2    = (const float*)d_in[13];
    const float* be2   = (const float*)d_in[14];
    const float* m2    = (const float*)d_in[15];
    const float* v2    = (const float*)d_in[16];
    const float* w_ds  = (const float*)d_in[17];
    const float* b_ds  = (const float*)d_in[18];
    const float* g3    = (const float*)d_in[19];
    const float* be3   = (const float*)d_in[20];
    const float* m3    = (const float*)d_in[21];
    const float* v3    = (const float*)d_in[22];

    const int C1 = 147456, C2 = 36864, C3 = 163840;
    char* wsp = (char*)d_ws;
    auto alloc = [&](size_t bytes) { char* r = wsp; wsp += (bytes + 255) & ~(size_t)255; return r; };
    const size_t szX0 = (size_t)NN * 66 * 66 * 128 * 2;
    const size_t szX1 = (size_t)NN * 67 * 67 * 128 * 2;
    u16*   Xpad0  = (u16*)alloc(szX0);
    u16*   Xpad1  = (u16*)alloc(szX1);
    u16*   Hpad0  = (u16*)alloc(szX0);
    u16*   Hpad1  = (u16*)alloc(szX1);
    float* OFFMSK = (float*)alloc((size_t)16900 * 32 * 4);
    u16*   T      = (u16*)alloc((size_t)16900 * 128 * 2);
    u16*   Wb1p   = (u16*)alloc((size_t)2 * C1 * 2);
    u16*   Wbomp  = (u16*)alloc((size_t)2 * C2 * 2);
    u16*   Wbdp   = (u16*)alloc((size_t)2 * C3 * 2);
    float* bias1f = (float*)alloc(2 * 128 * 4);
    float* biasOM = (float*)alloc(2 * 32 * 4);
    float* biasC  = (float*)alloc(2 * 128 * 4);

    // ---- merged prologue: border zero + layout + weight packing ---------
    const int B0 = NN * 260 * 16, B1 = NN * 264 * 16;
    int ptot = 2 * B0 + 2 * B1 + NN * 64 * 64 * 16 + 2 * C1 + 2 * C2 + 2 * C3 + 2 * 288;
    prolog_k<<<(ptot + 255) / 256, 256, 0, stream>>>(
        x0, Xpad0, Xpad1, Hpad0, Hpad1,
        w1, b1, g1, be1, m1, v1, w_off, b_off, w_mod, b_mod, w_def, b_def,
        g2, be2, m2, v2, w_ds, b_ds, g3, be3, m3, v3,
        Wb1p, Wbomp, Wbdp, bias1f, biasOM, biasC);

    const u16* curX = Xpad0;
    for (int i = 0; i < 2; ++i) {
        int H = 64 + i, W = 64 + i;
        int HW = H * W;
        int npb = (HW + 63) / 64;
        int grid = NN * npb;
        u16* Hpad = (i == 0) ? Hpad0 : Hpad1;

        // h = relu(bn1(conv3x3(x)))
        gconv_h<2, 4, 2, 2, 8, 0><<<grid, 512, 0, stream>>>(
            curX, Wb1p + (size_t)i * C1, bias1f + i * 128, Hpad, H, W, npb);
        // off(18) + msk(9, 2*sigmoid) -> OFFMSK [pix][32]
        gconv_h<4, 2, 1, 1, 2, 1><<<grid, 512, 0, stream>>>(
            Hpad, Wbomp + (size_t)i * C2, biasOM + i * 32, OFFMSK, H, W, npb);
        // fused deformable conv + residual + bn2/bn3 + relu (quarter-tile)
        int tw = (W + 3) / 4, th = (H + 3) / 4;
        deform9_k<<<NN * tw * th, 256, 0, stream>>>(
            Hpad, curX, OFFMSK, Wbdp + (size_t)i * C3, biasC + i * 128, T, H, W, tw, th);
        // maxpool
        if (i == 0) {
            pool_k<0><<<(NN * 65 * 65 * 16 + 255) / 256, 256, 0, stream>>>(T, Xpad1, H, W);
        } else {
            pool_k<1><<<(NN * 66 * 66 * 16 + 255) / 256, 256, 0, stream>>>(T, d_out, H, W);
        }
        curX = Xpad1;
    }
}